// Round 4
// baseline (1431.940 us; speedup 1.0000x reference)
//
#include <hip/hip_runtime.h>
#include <math.h>

#define BATCH 16384
#define EPSQ 1e-8f

// ---------------- ws layout (float offsets) ----------------
// scalars: [0] absmax_in
// [1] max_a1 [2] negmax_a1 (conv1 preact, pre-pool, incl bias)
// [3] max_a2 [4] negmax_a2 (conv2 preact)
// [5] max_a3 [6] negmax_a3 (fc1 preact)
// [7] max_a4 [8] negmax_a4 (fc2 preact)
#define OFF_SCAL 0
#define OFF_WQ1  16                         // 450   (6,3,5,5) binarized +-s
#define OFF_WQ2  (16+450)                   // 2400  (16,6,5,5)
#define OFF_FQ1  (16+450+2400)              // 48000 [120][400] binarized
#define OFF_FQ2  (OFF_FQ1+48000)            // 10080 [84][120]
#define OFF_FQ3  (OFF_FQ2+10080)            // 840   [10][84]
#define OFF_OUT1 62016                      // B*6*14*14 pooled conv1 preact
#define N_OUT1   (BATCH*6*14*14)
#define OFF_OUT2 (OFF_OUT1+N_OUT1)          // B*400 pooled conv2 preact
#define N_OUT2   (BATCH*400)
#define OFF_P3   (OFF_OUT2+N_OUT2)          // B*120 fc1 preact
#define N_P3     (BATCH*120)
#define OFF_P4   (OFF_P3+N_P3)              // B*84  fc2 preact
#define N_P4     (BATCH*84)

__device__ inline void atomicMaxF(float* addr, float val) {
    unsigned int* ua = (unsigned int*)addr;
    unsigned int old = *ua;
    while (__uint_as_float(old) < val) {
        unsigned int assumed = old;
        old = atomicCAS(ua, assumed, __float_as_uint(val));
        if (old == assumed) break;
    }
}

__device__ inline float waveMax(float v) {
    #pragma unroll
    for (int off = 32; off > 0; off >>= 1)
        v = fmaxf(v, __shfl_down(v, off, 64));
    return v;
}

// block of 256 threads = 4 waves
__device__ inline void blockAtomicMax2(float vmax, float vnmax, float* gmax, float* gnmax) {
    __shared__ float sm[4], sn[4];
    float a = waveMax(vmax), b = waveMax(vnmax);
    int tid = threadIdx.x;
    if ((tid & 63) == 0) { sm[tid >> 6] = a; sn[tid >> 6] = b; }
    __syncthreads();
    if (tid == 0) {
        float m = fmaxf(fmaxf(sm[0], sm[1]), fmaxf(sm[2], sm[3]));
        float n = fmaxf(fmaxf(sn[0], sn[1]), fmaxf(sn[2], sn[3]));
        atomicMaxF(gmax, m);
        atomicMaxF(gnmax, n);
    }
}

__device__ inline void waveAtomicMax2(float vmax, float vnmax, float* gmax, float* gnmax) {
    float a = waveMax(vmax), b = waveMax(vnmax);
    if ((threadIdx.x & 63) == 0) { atomicMaxF(gmax, a); atomicMaxF(gnmax, b); }
}

// int8 fake-quant (forward value); IEEE div matches jnp.round(x/s) bins
__device__ inline float fq_elem(float x, float s) {
    float q = fminf(fmaxf(rintf(x / s), -128.0f), 127.0f);
    return q * s;
}

__device__ inline float qrelu_elem(float x, float s1, float s2) {
    float q = fq_elem(x, s1);
    q = fmaxf(q, 0.0f);
    return fq_elem(q, s2);
}

__device__ inline void get_qrelu_scales(const float* scal, int slot, float& s1, float& s2) {
    float maxa = scal[slot], negm = scal[slot + 1];
    float absm = fmaxf(maxa, negm);
    s1 = fmaxf(absm / 127.0f, EPSQ);
    float qm = fminf(fmaxf(rintf(maxa / s1), -128.0f), 127.0f) * s1;
    s2 = fmaxf(fmaxf(qm, 0.0f) / 127.0f, EPSQ);
}

// ---------------- prep: init scalars + binarize weights ----------------
__global__ __launch_bounds__(256) void prep_kernel(const float* __restrict__ w1,
        const float* __restrict__ w2, const float* __restrict__ fw1,
        const float* __restrict__ fw2, const float* __restrict__ fw3,
        float* __restrict__ ws) {
    int blk = blockIdx.x, tid = threadIdx.x;
    float* scal = ws + OFF_SCAL;
    if (blk == 0) {
        if (tid == 0) scal[0] = 0.0f;
        else if (tid <= 8) scal[tid] = -INFINITY;
        return;
    }
    const float* src = nullptr; float* dst = nullptr; int N = 0;
    if (blk == 1)      { src = w1;  dst = ws + OFF_WQ1; N = 450; }
    else if (blk == 2) { src = w2;  dst = ws + OFF_WQ2; N = 2400; }
    else if (blk == 3) { src = fw1; dst = ws + OFF_FQ1; N = 48000; }
    else if (blk == 4) { src = fw2; dst = ws + OFF_FQ2; N = 10080; }
    else               { src = fw3; dst = ws + OFF_FQ3; N = 840; }
    __shared__ float red[256];
    __shared__ float sS;
    float partial = 0.0f;
    for (int i = tid; i < N; i += 256) partial += fabsf(src[i]);
    red[tid] = partial;
    __syncthreads();
    for (int s = 128; s > 0; s >>= 1) {
        if (tid < s) red[tid] += red[tid + s];
        __syncthreads();
    }
    if (tid == 0) sS = red[0] / (float)N;
    __syncthreads();
    float s = sS;
    for (int i = tid; i < N; i += 256) dst[i] = (src[i] >= 0.0f) ? s : -s;
}

// ---------------- input abs-max ----------------
__global__ __launch_bounds__(256) void absmax_kernel(const float4* __restrict__ x, int n4,
                                                     float* __restrict__ gmax) {
    float m = 0.0f;
    int stride = gridDim.x * 256;
    for (int i = blockIdx.x * 256 + threadIdx.x; i < n4; i += stride) {
        float4 v = x[i];
        m = fmaxf(m, fmaxf(fmaxf(fabsf(v.x), fabsf(v.y)), fmaxf(fabsf(v.z), fabsf(v.w))));
    }
    m = waveMax(m);
    if ((threadIdx.x & 63) == 0) atomicMaxF(gmax, m);
}

// ---------------- conv1: 1 image/block, thread = pooled position (all 6 channels) ----
// LDS: xq[3][32][36] fp32. Thread (py,px): 6x6 window per ci reused by 6 channels.
__global__ __launch_bounds__(256) void conv1_kernel(const float* __restrict__ x,
        const float* __restrict__ b1, float* __restrict__ ws) {
    __shared__ float xq[3 * 1152];   // ci stride 1152 = 32*36
    __shared__ float wsm[450];
    __shared__ float bsm[6];
    float* scal = ws + OFF_SCAL;
    float* out1 = ws + OFF_OUT1;
    int tid = threadIdx.x;
    int b = blockIdx.x;
    float s0 = fmaxf(scal[0] / 127.0f, EPSQ);

    const float4* xb = (const float4*)(x + (size_t)b * 3072);
    for (int i = tid; i < 768; i += 256) {
        float4 v = xb[i];
        v.x = fq_elem(v.x, s0); v.y = fq_elem(v.y, s0);
        v.z = fq_elem(v.z, s0); v.w = fq_elem(v.w, s0);
        int idx = i * 4;
        int ci = idx >> 10, r2 = idx & 1023;
        int row = r2 >> 5, col = r2 & 31;
        *(float4*)&xq[ci * 1152 + row * 36 + col] = v;
    }
    for (int i = tid; i < 450; i += 256) wsm[i] = ws[OFF_WQ1 + i];
    if (tid < 6) bsm[tid] = b1[tid];
    __syncthreads();

    float vmax = -INFINITY, vnmax = -INFINITY;
    if (tid < 196) {
        int py = tid / 14, px = tid % 14;
        float acc[6][4];
        #pragma unroll
        for (int c = 0; c < 6; c++) {
            float bv = bsm[c];
            acc[c][0] = bv; acc[c][1] = bv; acc[c][2] = bv; acc[c][3] = bv;
        }
        for (int ci = 0; ci < 3; ci++) {
            float win[6][6];
            const float* base = &xq[ci * 1152 + (2 * py) * 36 + 2 * px];
            #pragma unroll
            for (int r = 0; r < 6; r++) {
                float2 a = *(const float2*)(base + r * 36);
                float2 bb = *(const float2*)(base + r * 36 + 2);
                float2 cc = *(const float2*)(base + r * 36 + 4);
                win[r][0] = a.x;  win[r][1] = a.y;
                win[r][2] = bb.x; win[r][3] = bb.y;
                win[r][4] = cc.x; win[r][5] = cc.y;
            }
            #pragma unroll
            for (int c = 0; c < 6; c++) {
                const float* wp = &wsm[c * 75 + ci * 25];
                #pragma unroll
                for (int ky = 0; ky < 5; ky++) {
                    #pragma unroll
                    for (int kx = 0; kx < 5; kx++) {
                        float w = wp[ky * 5 + kx];
                        acc[c][0] = fmaf(win[ky][kx],         w, acc[c][0]);
                        acc[c][1] = fmaf(win[ky][kx + 1],     w, acc[c][1]);
                        acc[c][2] = fmaf(win[ky + 1][kx],     w, acc[c][2]);
                        acc[c][3] = fmaf(win[ky + 1][kx + 1], w, acc[c][3]);
                    }
                }
            }
        }
        #pragma unroll
        for (int c = 0; c < 6; c++) {
            float mx = fmaxf(fmaxf(acc[c][0], acc[c][1]), fmaxf(acc[c][2], acc[c][3]));
            float mn = fminf(fminf(acc[c][0], acc[c][1]), fminf(acc[c][2], acc[c][3]));
            vmax  = fmaxf(vmax, mx);
            vnmax = fmaxf(vnmax, -mn);
            out1[(size_t)b * 1176 + c * 196 + tid] = mx;
        }
    }
    blockAtomicMax2(vmax, vnmax, scal + 1, scal + 2);
}

// ---------------- conv2: 5 images/block, thread = (img, c-half, pooled pos) ----------
// LDS: act[img][6][14][16] fp32 (1344/img). Thread: 6x6 window per ci reused by 8 channels.
__global__ __launch_bounds__(256) void conv2_kernel(const float* __restrict__ b2,
                                                    float* __restrict__ ws) {
    __shared__ float act[5 * 1344];
    __shared__ float wsm[2400];
    __shared__ float bsm[16];
    float* scal = ws + OFF_SCAL;
    const float* out1 = ws + OFF_OUT1;
    float* out2 = ws + OFF_OUT2;
    int tid = threadIdx.x;
    int b0 = blockIdx.x * 5;
    int nimg = min(5, BATCH - b0);
    float s1, s2;
    get_qrelu_scales(scal, 1, s1, s2);

    for (int i = tid; i < nimg * 1176; i += 256) {
        int img = i / 1176, rem = i % 1176;
        int ci = rem / 196, r2 = rem % 196;
        int row = r2 / 14, col = r2 % 14;
        act[img * 1344 + ci * 224 + row * 16 + col] =
            qrelu_elem(out1[(size_t)(b0 + img) * 1176 + rem], s1, s2);
    }
    for (int i = tid; i < 2400; i += 256) wsm[i] = ws[OFF_WQ2 + i];
    if (tid < 16) bsm[tid] = b2[tid];
    __syncthreads();

    float vmax = -INFINITY, vnmax = -INFINITY;
    if (tid < nimg * 50) {
        int img = tid / 50, t = tid % 50;
        int half = t / 25, pos = t % 25;
        int py = pos / 5, px = pos % 5;
        int c0 = half * 8;
        float acc[8][4];
        #pragma unroll
        for (int c = 0; c < 8; c++) {
            float bv = bsm[c0 + c];
            acc[c][0] = bv; acc[c][1] = bv; acc[c][2] = bv; acc[c][3] = bv;
        }
        for (int ci = 0; ci < 6; ci++) {
            float win[6][6];
            const float* base = &act[img * 1344 + ci * 224 + (2 * py) * 16 + 2 * px];
            #pragma unroll
            for (int r = 0; r < 6; r++) {
                float2 a = *(const float2*)(base + r * 16);
                float2 bb = *(const float2*)(base + r * 16 + 2);
                float2 cc = *(const float2*)(base + r * 16 + 4);
                win[r][0] = a.x;  win[r][1] = a.y;
                win[r][2] = bb.x; win[r][3] = bb.y;
                win[r][4] = cc.x; win[r][5] = cc.y;
            }
            #pragma unroll
            for (int c = 0; c < 8; c++) {
                const float* wp = &wsm[(c0 + c) * 150 + ci * 25];
                #pragma unroll
                for (int ky = 0; ky < 5; ky++) {
                    #pragma unroll
                    for (int kx = 0; kx < 5; kx++) {
                        float w = wp[ky * 5 + kx];
                        acc[c][0] = fmaf(win[ky][kx],         w, acc[c][0]);
                        acc[c][1] = fmaf(win[ky][kx + 1],     w, acc[c][1]);
                        acc[c][2] = fmaf(win[ky + 1][kx],     w, acc[c][2]);
                        acc[c][3] = fmaf(win[ky + 1][kx + 1], w, acc[c][3]);
                    }
                }
            }
        }
        #pragma unroll
        for (int c = 0; c < 8; c++) {
            float mx = fmaxf(fmaxf(acc[c][0], acc[c][1]), fmaxf(acc[c][2], acc[c][3]));
            float mn = fminf(fminf(acc[c][0], acc[c][1]), fminf(acc[c][2], acc[c][3]));
            vmax  = fmaxf(vmax, mx);
            vnmax = fmaxf(vnmax, -mn);
            out2[(size_t)(b0 + img) * 400 + (c0 + c) * 25 + pos] = mx;
        }
    }
    blockAtomicMax2(vmax, vnmax, scal + 3, scal + 4);
}

// ---------------- fc1: [B,400]->[B,120], 8 rows/block ----------------
__global__ __launch_bounds__(128) void fc1_kernel(const float* __restrict__ fb1,
                                                  float* __restrict__ ws) {
    __shared__ float xs[8][400];
    float* scal = ws + OFF_SCAL;
    const float* p2 = ws + OFF_OUT2;
    const float* wq = ws + OFF_FQ1;   // [120][400]
    float* p3 = ws + OFF_P3;
    int tid = threadIdx.x;
    size_t row0 = (size_t)blockIdx.x * 8;
    float s1, s2;
    get_qrelu_scales(scal, 3, s1, s2);
    const float4* src = (const float4*)(p2 + row0 * 400);
    for (int i = tid; i < 800; i += 128) {
        float4 v = src[i];
        v.x = qrelu_elem(v.x, s1, s2); v.y = qrelu_elem(v.y, s1, s2);
        v.z = qrelu_elem(v.z, s1, s2); v.w = qrelu_elem(v.w, s1, s2);
        ((float4*)xs)[i] = v;
    }
    __syncthreads();
    float vmax = -INFINITY, vnmax = -INFINITY;
    if (tid < 120) {
        int j = tid;
        float acc[8];
        float bias = fb1[j];
        #pragma unroll
        for (int r = 0; r < 8; r++) acc[r] = bias;
        const float4* wr = (const float4*)(wq + j * 400);
        for (int k4 = 0; k4 < 100; k4++) {
            float4 w = wr[k4];
            #pragma unroll
            for (int r = 0; r < 8; r++) {
                float4 xv = *(const float4*)&xs[r][k4 * 4];
                acc[r] = fmaf(xv.x, w.x, acc[r]);
                acc[r] = fmaf(xv.y, w.y, acc[r]);
                acc[r] = fmaf(xv.z, w.z, acc[r]);
                acc[r] = fmaf(xv.w, w.w, acc[r]);
            }
        }
        #pragma unroll
        for (int r = 0; r < 8; r++) {
            p3[(row0 + r) * 120 + j] = acc[r];
            vmax = fmaxf(vmax, acc[r]); vnmax = fmaxf(vnmax, -acc[r]);
        }
    }
    waveAtomicMax2(vmax, vnmax, scal + 5, scal + 6);
}

// ---------------- fc2: [B,120]->[B,84], 8 rows/block ----------------
__global__ __launch_bounds__(128) void fc2_kernel(const float* __restrict__ fb2,
                                                  float* __restrict__ ws) {
    __shared__ float xs[8][120];
    float* scal = ws + OFF_SCAL;
    const float* p3 = ws + OFF_P3;
    const float* wq = ws + OFF_FQ2;   // [84][120]
    float* p4 = ws + OFF_P4;
    int tid = threadIdx.x;
    size_t row0 = (size_t)blockIdx.x * 8;
    float s1, s2;
    get_qrelu_scales(scal, 5, s1, s2);
    const float4* src = (const float4*)(p3 + row0 * 120);
    for (int i = tid; i < 240; i += 128) {
        float4 v = src[i];
        v.x = qrelu_elem(v.x, s1, s2); v.y = qrelu_elem(v.y, s1, s2);
        v.z = qrelu_elem(v.z, s1, s2); v.w = qrelu_elem(v.w, s1, s2);
        ((float4*)xs)[i] = v;
    }
    __syncthreads();
    float vmax = -INFINITY, vnmax = -INFINITY;
    if (tid < 84) {
        int j = tid;
        float acc[8];
        float bias = fb2[j];
        #pragma unroll
        for (int r = 0; r < 8; r++) acc[r] = bias;
        const float4* wr = (const float4*)(wq + j * 120);
        for (int k4 = 0; k4 < 30; k4++) {
            float4 w = wr[k4];
            #pragma unroll
            for (int r = 0; r < 8; r++) {
                float4 xv = *(const float4*)&xs[r][k4 * 4];
                acc[r] = fmaf(xv.x, w.x, acc[r]);
                acc[r] = fmaf(xv.y, w.y, acc[r]);
                acc[r] = fmaf(xv.z, w.z, acc[r]);
                acc[r] = fmaf(xv.w, w.w, acc[r]);
            }
        }
        #pragma unroll
        for (int r = 0; r < 8; r++) {
            p4[(row0 + r) * 84 + j] = acc[r];
            vmax = fmaxf(vmax, acc[r]); vnmax = fmaxf(vnmax, -acc[r]);
        }
    }
    waveAtomicMax2(vmax, vnmax, scal + 7, scal + 8);
}

// ---------------- fc3: [B,84]->[B,10], 1 row/thread ----------------
__global__ __launch_bounds__(256) void fc3_kernel(const float* __restrict__ fb3,
                                                  float* __restrict__ out,
                                                  float* __restrict__ ws) {
    __shared__ float wsm[840];
    __shared__ float bs[10];
    float* scal = ws + OFF_SCAL;
    const float* p4 = ws + OFF_P4;
    int tid = threadIdx.x;
    for (int i = tid; i < 840; i += 256) wsm[i] = ws[OFF_FQ3 + i];
    if (tid < 10) bs[tid] = fb3[tid];
    __syncthreads();
    float s1, s2;
    get_qrelu_scales(scal, 7, s1, s2);
    size_t row = (size_t)blockIdx.x * 256 + tid;
    float acc[10];
    #pragma unroll
    for (int j = 0; j < 10; j++) acc[j] = bs[j];
    const float4* src = (const float4*)(p4 + row * 84);
    for (int k4 = 0; k4 < 21; k4++) {
        float4 v = src[k4];
        v.x = qrelu_elem(v.x, s1, s2); v.y = qrelu_elem(v.y, s1, s2);
        v.z = qrelu_elem(v.z, s1, s2); v.w = qrelu_elem(v.w, s1, s2);
        #pragma unroll
        for (int j = 0; j < 10; j++) {
            acc[j] = fmaf(v.x, wsm[j * 84 + k4 * 4 + 0], acc[j]);
            acc[j] = fmaf(v.y, wsm[j * 84 + k4 * 4 + 1], acc[j]);
            acc[j] = fmaf(v.z, wsm[j * 84 + k4 * 4 + 2], acc[j]);
            acc[j] = fmaf(v.w, wsm[j * 84 + k4 * 4 + 3], acc[j]);
        }
    }
    #pragma unroll
    for (int j = 0; j < 10; j++) out[row * 10 + j] = acc[j];
}

extern "C" void kernel_launch(void* const* d_in, const int* in_sizes, int n_in,
                              void* d_out, int out_size, void* d_ws, size_t ws_size,
                              hipStream_t stream) {
    const float* input = (const float*)d_in[0];
    const float* w1  = (const float*)d_in[1];
    const float* b1  = (const float*)d_in[2];
    const float* w2  = (const float*)d_in[3];
    const float* b2  = (const float*)d_in[4];
    const float* fw1 = (const float*)d_in[5];
    const float* fb1 = (const float*)d_in[6];
    const float* fw2 = (const float*)d_in[7];
    const float* fb2 = (const float*)d_in[8];
    const float* fw3 = (const float*)d_in[9];
    const float* fb3 = (const float*)d_in[10];
    float* ws  = (float*)d_ws;
    float* out = (float*)d_out;

    prep_kernel<<<6, 256, 0, stream>>>(w1, w2, fw1, fw2, fw3, ws);
    absmax_kernel<<<2048, 256, 0, stream>>>((const float4*)input,
                                            (int)((size_t)BATCH * 3072 / 4), ws + OFF_SCAL);
    conv1_kernel<<<BATCH, 256, 0, stream>>>(input, b1, ws);
    conv2_kernel<<<(BATCH + 4) / 5, 256, 0, stream>>>(b2, ws);
    fc1_kernel<<<BATCH / 8, 128, 0, stream>>>(fb1, ws);
    fc2_kernel<<<BATCH / 8, 128, 0, stream>>>(fb2, ws);
    fc3_kernel<<<BATCH / 256, 256, 0, stream>>>(fb3, out, ws);
}

// Round 5
// 999.472 us; speedup vs baseline: 1.4327x; 1.4327x over previous
//
#include <hip/hip_runtime.h>
#include <math.h>

#define BATCH 16384
#define EPSQ 1e-8f

// ---------------- ws layout (float offsets) ----------------
// scalars: [0] absmax_in
// [1] max_a1 [2] negmax_a1 (conv1 preact, pre-pool, incl bias)
// [3] max_a2 [4] negmax_a2 (conv2 preact)
// [5] max_a3 [6] negmax_a3 (fc1 preact)
// [7] max_a4 [8] negmax_a4 (fc2 preact)
#define OFF_SCAL 0
#define OFF_WQ1  16                         // 450   (6,3,5,5) binarized +-s
#define OFF_WQ2  (16+450)                   // 2400  (16,6,5,5)
#define OFF_FQ1  (16+450+2400)              // 48000 [120][400] binarized
#define OFF_FQ2  (OFF_FQ1+48000)            // 10080 [84][120]
#define OFF_FQ3  (OFF_FQ2+10080)            // 840   [10][84]
#define OFF_OUT1 62016                      // B*6*14*14 pooled conv1 preact
#define N_OUT1   (BATCH*6*14*14)
#define OFF_OUT2 (OFF_OUT1+N_OUT1)          // B*400 pooled conv2 preact
#define N_OUT2   (BATCH*400)
#define OFF_P3   (OFF_OUT2+N_OUT2)          // B*120 fc1 preact
#define N_P3     (BATCH*120)
#define OFF_P4   (OFF_P3+N_P3)              // B*84  fc2 preact
#define N_P4     (BATCH*84)

__device__ inline void atomicMaxF(float* addr, float val) {
    unsigned int* ua = (unsigned int*)addr;
    unsigned int old = *ua;
    while (__uint_as_float(old) < val) {
        unsigned int assumed = old;
        old = atomicCAS(ua, assumed, __float_as_uint(val));
        if (old == assumed) break;
    }
}

__device__ inline float waveMax(float v) {
    #pragma unroll
    for (int off = 32; off > 0; off >>= 1)
        v = fmaxf(v, __shfl_down(v, off, 64));
    return v;
}

// block of 256 threads = 4 waves
__device__ inline void blockAtomicMax2(float vmax, float vnmax, float* gmax, float* gnmax) {
    __shared__ float sm[4], sn[4];
    float a = waveMax(vmax), b = waveMax(vnmax);
    int tid = threadIdx.x;
    if ((tid & 63) == 0) { sm[tid >> 6] = a; sn[tid >> 6] = b; }
    __syncthreads();
    if (tid == 0) {
        float m = fmaxf(fmaxf(sm[0], sm[1]), fmaxf(sm[2], sm[3]));
        float n = fmaxf(fmaxf(sn[0], sn[1]), fmaxf(sn[2], sn[3]));
        atomicMaxF(gmax, m);
        atomicMaxF(gnmax, n);
    }
}

__device__ inline void waveAtomicMax2(float vmax, float vnmax, float* gmax, float* gnmax) {
    float a = waveMax(vmax), b = waveMax(vnmax);
    if ((threadIdx.x & 63) == 0) { atomicMaxF(gmax, a); atomicMaxF(gnmax, b); }
}

// int8 fake-quant (forward value); IEEE div matches jnp.round(x/s) bins
__device__ inline float fq_elem(float x, float s) {
    float q = fminf(fmaxf(rintf(x / s), -128.0f), 127.0f);
    return q * s;
}

__device__ inline float qrelu_elem(float x, float s1, float s2) {
    float q = fq_elem(x, s1);
    q = fmaxf(q, 0.0f);
    return fq_elem(q, s2);
}

// qrelu returning INTEGER code r (value = r*s2); r in [0,127], exact in bf16
__device__ inline float qrelu_code(float x, float s1, float s2) {
    float q = fq_elem(x, s1);
    q = fmaxf(q, 0.0f);
    return fminf(fmaxf(rintf(q / s2), -128.0f), 127.0f);
}

__device__ inline void get_qrelu_scales(const float* scal, int slot, float& s1, float& s2) {
    float maxa = scal[slot], negm = scal[slot + 1];
    float absm = fmaxf(maxa, negm);
    s1 = fmaxf(absm / 127.0f, EPSQ);
    float qm = fminf(fmaxf(rintf(maxa / s1), -128.0f), 127.0f) * s1;
    s2 = fmaxf(fmaxf(qm, 0.0f) / 127.0f, EPSQ);
}

// unpack 2 bf16 codes from one u32; value = code * sc (exactly R2's q*s arithmetic)
__device__ inline void unpack2(unsigned int u, float sc, float& f0, float& f1) {
    f0 = __uint_as_float(u << 16) * sc;
    f1 = __uint_as_float(u & 0xffff0000u) * sc;
}

// ---------------- prep: init scalars + binarize weights ----------------
__global__ __launch_bounds__(256) void prep_kernel(const float* __restrict__ w1,
        const float* __restrict__ w2, const float* __restrict__ fw1,
        const float* __restrict__ fw2, const float* __restrict__ fw3,
        float* __restrict__ ws) {
    int blk = blockIdx.x, tid = threadIdx.x;
    float* scal = ws + OFF_SCAL;
    if (blk == 0) {
        if (tid == 0) scal[0] = 0.0f;
        else if (tid <= 8) scal[tid] = -INFINITY;
        return;
    }
    const float* src = nullptr; float* dst = nullptr; int N = 0;
    if (blk == 1)      { src = w1;  dst = ws + OFF_WQ1; N = 450; }
    else if (blk == 2) { src = w2;  dst = ws + OFF_WQ2; N = 2400; }
    else if (blk == 3) { src = fw1; dst = ws + OFF_FQ1; N = 48000; }
    else if (blk == 4) { src = fw2; dst = ws + OFF_FQ2; N = 10080; }
    else               { src = fw3; dst = ws + OFF_FQ3; N = 840; }
    __shared__ float red[256];
    __shared__ float sS;
    float partial = 0.0f;
    for (int i = tid; i < N; i += 256) partial += fabsf(src[i]);
    red[tid] = partial;
    __syncthreads();
    for (int s = 128; s > 0; s >>= 1) {
        if (tid < s) red[tid] += red[tid + s];
        __syncthreads();
    }
    if (tid == 0) sS = red[0] / (float)N;
    __syncthreads();
    float s = sS;
    for (int i = tid; i < N; i += 256) dst[i] = (src[i] >= 0.0f) ? s : -s;
}

// ---------------- input abs-max ----------------
__global__ __launch_bounds__(256) void absmax_kernel(const float4* __restrict__ x, int n4,
                                                     float* __restrict__ gmax) {
    float m = 0.0f;
    int stride = gridDim.x * 256;
    for (int i = blockIdx.x * 256 + threadIdx.x; i < n4; i += stride) {
        float4 v = x[i];
        m = fmaxf(m, fmaxf(fmaxf(fabsf(v.x), fabsf(v.y)), fmaxf(fabsf(v.z), fabsf(v.w))));
    }
    m = waveMax(m);
    if ((threadIdx.x & 63) == 0) atomicMaxF(gmax, m);
}

// ---------------- conv1: 3 images/block, bf16-code LDS, row-sliding, x-split ----
// LDS codes: xq[img][ci][32][40] shorts. img stride 3840, ci stride 1280.
// Thread = (img, c, py): computes pre-pool rows 2py,2py+1 in two x-phases.
#define C1_PP   40
#define C1_CIS  1280
#define C1_IMGS 3840
__global__ __launch_bounds__(256) void conv1_kernel(const float* __restrict__ x,
        const float* __restrict__ b1, float* __restrict__ ws) {
    __shared__ unsigned short xq[3 * C1_IMGS];
    __shared__ float wsm[450];
    float* scal = ws + OFF_SCAL;
    float* out1 = ws + OFF_OUT1;
    int tid = threadIdx.x;
    int b0 = blockIdx.x * 3;
    int nimg = min(3, BATCH - b0);
    float sc0 = fmaxf(scal[0] / 127.0f, EPSQ);

    // stage integer codes as bf16 (exact); 2 floats -> 1 u32 LDS write
    const float2* xb = (const float2*)(x + (size_t)b0 * 3072);
    for (int i = tid; i < nimg * 1536; i += 256) {
        float2 v = xb[i];
        float q0 = fminf(fmaxf(rintf(v.x / sc0), -128.0f), 127.0f);
        float q1 = fminf(fmaxf(rintf(v.y / sc0), -128.0f), 127.0f);
        unsigned int u = (__float_as_uint(q0) >> 16) | (__float_as_uint(q1) & 0xffff0000u);
        int idx = i * 2;
        int img = idx / 3072, rem = idx % 3072;
        int ci = rem >> 10, r2 = rem & 1023;
        int row = r2 >> 5, col = r2 & 31;
        *(unsigned int*)&xq[img * C1_IMGS + ci * C1_CIS + row * C1_PP + col] = u;
    }
    for (int i = tid; i < 450; i += 256) wsm[i] = ws[OFF_WQ1 + i];
    __syncthreads();

    float vmax = -INFINITY, vnmax = -INFINITY;
    if (tid < nimg * 84) {
        int img = tid / 84, r = tid % 84;
        int c = r / 14, py = r % 14;
        float bias = b1[c];
        const float* wc = &wsm[c * 75];
        const unsigned short* ibase = &xq[img * C1_IMGS];
        float pool[14];

        // ---- phase 0: outputs x = 0..11 (cols 0..15) ----
        {
            float a0[12], a1[12];
            #pragma unroll
            for (int i = 0; i < 12; i++) { a0[i] = bias; a1[i] = bias; }
            for (int ci = 0; ci < 3; ci++) {
                const unsigned short* rb = ibase + ci * C1_CIS + (2 * py) * C1_PP;
                const float* wci = wc + ci * 25;
                #pragma unroll
                for (int t = 0; t < 6; t++) {
                    uint4 u0 = *(const uint4*)(rb + t * C1_PP);      // codes 0..7
                    uint4 u1 = *(const uint4*)(rb + t * C1_PP + 8);  // codes 8..15
                    float row[16];
                    unpack2(u0.x, sc0, row[0],  row[1]);
                    unpack2(u0.y, sc0, row[2],  row[3]);
                    unpack2(u0.z, sc0, row[4],  row[5]);
                    unpack2(u0.w, sc0, row[6],  row[7]);
                    unpack2(u1.x, sc0, row[8],  row[9]);
                    unpack2(u1.y, sc0, row[10], row[11]);
                    unpack2(u1.z, sc0, row[12], row[13]);
                    unpack2(u1.w, sc0, row[14], row[15]);
                    if (t <= 4) {
                        #pragma unroll
                        for (int kx = 0; kx < 5; kx++) {
                            float w0 = wci[t * 5 + kx];
                            #pragma unroll
                            for (int col = 0; col < 12; col++)
                                a0[col] = fmaf(row[col + kx], w0, a0[col]);
                        }
                    }
                    if (t >= 1) {
                        #pragma unroll
                        for (int kx = 0; kx < 5; kx++) {
                            float w1v = wci[(t - 1) * 5 + kx];
                            #pragma unroll
                            for (int col = 0; col < 12; col++)
                                a1[col] = fmaf(row[col + kx], w1v, a1[col]);
                        }
                    }
                }
            }
            #pragma unroll
            for (int i = 0; i < 12; i++) {
                vmax  = fmaxf(vmax,  fmaxf(a0[i], a1[i]));
                vnmax = fmaxf(vnmax, fmaxf(-a0[i], -a1[i]));
            }
            #pragma unroll
            for (int px = 0; px < 6; px++)
                pool[px] = fmaxf(fmaxf(a0[2 * px], a0[2 * px + 1]),
                                 fmaxf(a1[2 * px], a1[2 * px + 1]));
        }

        // ---- phase 1: outputs x = 12..27 (cols 12..31; read codes 8..31) ----
        {
            float a0[16], a1[16];
            #pragma unroll
            for (int i = 0; i < 16; i++) { a0[i] = bias; a1[i] = bias; }
            for (int ci = 0; ci < 3; ci++) {
                const unsigned short* rb = ibase + ci * C1_CIS + (2 * py) * C1_PP;
                const float* wci = wc + ci * 25;
                #pragma unroll
                for (int t = 0; t < 6; t++) {
                    uint4 u0 = *(const uint4*)(rb + t * C1_PP + 8);   // codes 8..15
                    uint4 u1 = *(const uint4*)(rb + t * C1_PP + 16);  // codes 16..23
                    uint4 u2 = *(const uint4*)(rb + t * C1_PP + 24);  // codes 24..31
                    float row[24];                                     // row[j] = code 8+j
                    unpack2(u0.x, sc0, row[0],  row[1]);
                    unpack2(u0.y, sc0, row[2],  row[3]);
                    unpack2(u0.z, sc0, row[4],  row[5]);
                    unpack2(u0.w, sc0, row[6],  row[7]);
                    unpack2(u1.x, sc0, row[8],  row[9]);
                    unpack2(u1.y, sc0, row[10], row[11]);
                    unpack2(u1.z, sc0, row[12], row[13]);
                    unpack2(u1.w, sc0, row[14], row[15]);
                    unpack2(u2.x, sc0, row[16], row[17]);
                    unpack2(u2.y, sc0, row[18], row[19]);
                    unpack2(u2.z, sc0, row[20], row[21]);
                    unpack2(u2.w, sc0, row[22], row[23]);
                    if (t <= 4) {
                        #pragma unroll
                        for (int kx = 0; kx < 5; kx++) {
                            float w0 = wci[t * 5 + kx];
                            #pragma unroll
                            for (int m = 0; m < 16; m++)       // x = 12+m, col = x+kx -> row[m+4+kx]
                                a0[m] = fmaf(row[m + 4 + kx], w0, a0[m]);
                        }
                    }
                    if (t >= 1) {
                        #pragma unroll
                        for (int kx = 0; kx < 5; kx++) {
                            float w1v = wci[(t - 1) * 5 + kx];
                            #pragma unroll
                            for (int m = 0; m < 16; m++)
                                a1[m] = fmaf(row[m + 4 + kx], w1v, a1[m]);
                        }
                    }
                }
            }
            #pragma unroll
            for (int i = 0; i < 16; i++) {
                vmax  = fmaxf(vmax,  fmaxf(a0[i], a1[i]));
                vnmax = fmaxf(vnmax, fmaxf(-a0[i], -a1[i]));
            }
            #pragma unroll
            for (int p = 0; p < 8; p++)
                pool[6 + p] = fmaxf(fmaxf(a0[2 * p], a0[2 * p + 1]),
                                    fmaxf(a1[2 * p], a1[2 * p + 1]));
        }

        float* dst = &out1[(size_t)(b0 + img) * 1176 + c * 196 + py * 14];
        #pragma unroll
        for (int px = 0; px < 14; px++) dst[px] = pool[px];
    }
    blockAtomicMax2(vmax, vnmax, scal + 1, scal + 2);
}

// ---------------- conv2: 3 images/block, bf16-code LDS, row-sliding ----------------
// LDS codes: act[img][ci][14][16] shorts. img stride 1344, ci stride 224.
#define C2_PP   16
#define C2_CIS  224
#define C2_IMGS 1344
__global__ __launch_bounds__(256) void conv2_kernel(const float* __restrict__ b2,
                                                    float* __restrict__ ws) {
    __shared__ unsigned short act[3 * C2_IMGS];
    __shared__ float wsm[2400];
    float* scal = ws + OFF_SCAL;
    const float* out1 = ws + OFF_OUT1;
    float* out2 = ws + OFF_OUT2;
    int tid = threadIdx.x;
    int b0 = blockIdx.x * 3;
    int nimg = min(3, BATCH - b0);
    float s1, s2;
    get_qrelu_scales(scal, 1, s1, s2);

    // stage integer codes (value = r*s2); 2 preacts -> 1 u32 write
    for (int i = tid; i < nimg * 588; i += 256) {
        int img = i / 588, rem = i % 588;
        int e = rem * 2;
        int ci = e / 196, r2 = e % 196;
        int row = r2 / 14, col = r2 % 14;
        float2 v = *(const float2*)&out1[(size_t)(b0 + img) * 1176 + e];
        float r0 = qrelu_code(v.x, s1, s2);
        float r1 = qrelu_code(v.y, s1, s2);
        unsigned int u = (__float_as_uint(r0) >> 16) | (__float_as_uint(r1) & 0xffff0000u);
        *(unsigned int*)&act[img * C2_IMGS + ci * C2_CIS + row * C2_PP + col] = u;
    }
    for (int i = tid; i < 2400; i += 256) wsm[i] = ws[OFF_WQ2 + i];
    __syncthreads();

    float vmax = -INFINITY, vnmax = -INFINITY;
    if (tid < nimg * 80) {
        int img = tid / 80, r = tid % 80;
        int c = r / 5, py = r % 5;
        float bias = b2[c];
        float a0[10], a1[10];
        #pragma unroll
        for (int i = 0; i < 10; i++) { a0[i] = bias; a1[i] = bias; }
        const float* wc = &wsm[c * 150];
        for (int ci = 0; ci < 6; ci++) {
            const unsigned short* rb = &act[img * C2_IMGS + ci * C2_CIS + (2 * py) * C2_PP];
            const float* wci = wc + ci * 25;
            #pragma unroll
            for (int t = 0; t < 6; t++) {
                uint4 u0 = *(const uint4*)(rb + t * C2_PP);      // codes 0..7
                uint4 u1 = *(const uint4*)(rb + t * C2_PP + 8);  // codes 8..15 (14,15 pad)
                float row[16];
                unpack2(u0.x, s2, row[0],  row[1]);
                unpack2(u0.y, s2, row[2],  row[3]);
                unpack2(u0.z, s2, row[4],  row[5]);
                unpack2(u0.w, s2, row[6],  row[7]);
                unpack2(u1.x, s2, row[8],  row[9]);
                unpack2(u1.y, s2, row[10], row[11]);
                unpack2(u1.z, s2, row[12], row[13]);
                unpack2(u1.w, s2, row[14], row[15]);
                if (t <= 4) {
                    #pragma unroll
                    for (int kx = 0; kx < 5; kx++) {
                        float w0 = wci[t * 5 + kx];
                        #pragma unroll
                        for (int col = 0; col < 10; col++)
                            a0[col] = fmaf(row[col + kx], w0, a0[col]);
                    }
                }
                if (t >= 1) {
                    #pragma unroll
                    for (int kx = 0; kx < 5; kx++) {
                        float w1v = wci[(t - 1) * 5 + kx];
                        #pragma unroll
                        for (int col = 0; col < 10; col++)
                            a1[col] = fmaf(row[col + kx], w1v, a1[col]);
                    }
                }
            }
        }
        #pragma unroll
        for (int i = 0; i < 10; i++) {
            vmax  = fmaxf(vmax,  fmaxf(a0[i], a1[i]));
            vnmax = fmaxf(vnmax, fmaxf(-a0[i], -a1[i]));
        }
        float* dst = &out2[(size_t)(b0 + img) * 400 + c * 25 + py * 5];
        #pragma unroll
        for (int px = 0; px < 5; px++)
            dst[px] = fmaxf(fmaxf(a0[2 * px], a0[2 * px + 1]),
                            fmaxf(a1[2 * px], a1[2 * px + 1]));
    }
    blockAtomicMax2(vmax, vnmax, scal + 3, scal + 4);
}

// ---------------- fc1: [B,400]->[B,120], 8 rows/block ----------------
__global__ __launch_bounds__(128) void fc1_kernel(const float* __restrict__ fb1,
                                                  float* __restrict__ ws) {
    __shared__ float xs[8][400];
    float* scal = ws + OFF_SCAL;
    const float* p2 = ws + OFF_OUT2;
    const float* wq = ws + OFF_FQ1;   // [120][400]
    float* p3 = ws + OFF_P3;
    int tid = threadIdx.x;
    size_t row0 = (size_t)blockIdx.x * 8;
    float s1, s2;
    get_qrelu_scales(scal, 3, s1, s2);
    const float4* src = (const float4*)(p2 + row0 * 400);
    for (int i = tid; i < 800; i += 128) {
        float4 v = src[i];
        v.x = qrelu_elem(v.x, s1, s2); v.y = qrelu_elem(v.y, s1, s2);
        v.z = qrelu_elem(v.z, s1, s2); v.w = qrelu_elem(v.w, s1, s2);
        ((float4*)xs)[i] = v;
    }
    __syncthreads();
    float vmax = -INFINITY, vnmax = -INFINITY;
    if (tid < 120) {
        int j = tid;
        float acc[8];
        float bias = fb1[j];
        #pragma unroll
        for (int r = 0; r < 8; r++) acc[r] = bias;
        const float4* wr = (const float4*)(wq + j * 400);
        for (int k4 = 0; k4 < 100; k4++) {
            float4 w = wr[k4];
            #pragma unroll
            for (int r = 0; r < 8; r++) {
                float4 xv = *(const float4*)&xs[r][k4 * 4];
                acc[r] = fmaf(xv.x, w.x, acc[r]);
                acc[r] = fmaf(xv.y, w.y, acc[r]);
                acc[r] = fmaf(xv.z, w.z, acc[r]);
                acc[r] = fmaf(xv.w, w.w, acc[r]);
            }
        }
        #pragma unroll
        for (int r = 0; r < 8; r++) {
            p3[(row0 + r) * 120 + j] = acc[r];
            vmax = fmaxf(vmax, acc[r]); vnmax = fmaxf(vnmax, -acc[r]);
        }
    }
    waveAtomicMax2(vmax, vnmax, scal + 5, scal + 6);
}

// ---------------- fc2: [B,120]->[B,84], 8 rows/block ----------------
__global__ __launch_bounds__(128) void fc2_kernel(const float* __restrict__ fb2,
                                                  float* __restrict__ ws) {
    __shared__ float xs[8][120];
    float* scal = ws + OFF_SCAL;
    const float* p3 = ws + OFF_P3;
    const float* wq = ws + OFF_FQ2;   // [84][120]
    float* p4 = ws + OFF_P4;
    int tid = threadIdx.x;
    size_t row0 = (size_t)blockIdx.x * 8;
    float s1, s2;
    get_qrelu_scales(scal, 5, s1, s2);
    const float4* src = (const float4*)(p3 + row0 * 120);
    for (int i = tid; i < 240; i += 128) {
        float4 v = src[i];
        v.x = qrelu_elem(v.x, s1, s2); v.y = qrelu_elem(v.y, s1, s2);
        v.z = qrelu_elem(v.z, s1, s2); v.w = qrelu_elem(v.w, s1, s2);
        ((float4*)xs)[i] = v;
    }
    __syncthreads();
    float vmax = -INFINITY, vnmax = -INFINITY;
    if (tid < 84) {
        int j = tid;
        float acc[8];
        float bias = fb2[j];
        #pragma unroll
        for (int r = 0; r < 8; r++) acc[r] = bias;
        const float4* wr = (const float4*)(wq + j * 120);
        for (int k4 = 0; k4 < 30; k4++) {
            float4 w = wr[k4];
            #pragma unroll
            for (int r = 0; r < 8; r++) {
                float4 xv = *(const float4*)&xs[r][k4 * 4];
                acc[r] = fmaf(xv.x, w.x, acc[r]);
                acc[r] = fmaf(xv.y, w.y, acc[r]);
                acc[r] = fmaf(xv.z, w.z, acc[r]);
                acc[r] = fmaf(xv.w, w.w, acc[r]);
            }
        }
        #pragma unroll
        for (int r = 0; r < 8; r++) {
            p4[(row0 + r) * 84 + j] = acc[r];
            vmax = fmaxf(vmax, acc[r]); vnmax = fmaxf(vnmax, -acc[r]);
        }
    }
    waveAtomicMax2(vmax, vnmax, scal + 7, scal + 8);
}

// ---------------- fc3: [B,84]->[B,10], 1 row/thread ----------------
__global__ __launch_bounds__(256) void fc3_kernel(const float* __restrict__ fb3,
                                                  float* __restrict__ out,
                                                  float* __restrict__ ws) {
    __shared__ float wsm[840];
    __shared__ float bs[10];
    float* scal = ws + OFF_SCAL;
    const float* p4 = ws + OFF_P4;
    int tid = threadIdx.x;
    for (int i = tid; i < 840; i += 256) wsm[i] = ws[OFF_FQ3 + i];
    if (tid < 10) bs[tid] = fb3[tid];
    __syncthreads();
    float s1, s2;
    get_qrelu_scales(scal, 7, s1, s2);
    size_t row = (size_t)blockIdx.x * 256 + tid;
    float acc[10];
    #pragma unroll
    for (int j = 0; j < 10; j++) acc[j] = bs[j];
    const float4* src = (const float4*)(p4 + row * 84);
    for (int k4 = 0; k4 < 21; k4++) {
        float4 v = src[k4];
        v.x = qrelu_elem(v.x, s1, s2); v.y = qrelu_elem(v.y, s1, s2);
        v.z = qrelu_elem(v.z, s1, s2); v.w = qrelu_elem(v.w, s1, s2);
        #pragma unroll
        for (int j = 0; j < 10; j++) {
            acc[j] = fmaf(v.x, wsm[j * 84 + k4 * 4 + 0], acc[j]);
            acc[j] = fmaf(v.y, wsm[j * 84 + k4 * 4 + 1], acc[j]);
            acc[j] = fmaf(v.z, wsm[j * 84 + k4 * 4 + 2], acc[j]);
            acc[j] = fmaf(v.w, wsm[j * 84 + k4 * 4 + 3], acc[j]);
        }
    }
    #pragma unroll
    for (int j = 0; j < 10; j++) out[row * 10 + j] = acc[j];
}

extern "C" void kernel_launch(void* const* d_in, const int* in_sizes, int n_in,
                              void* d_out, int out_size, void* d_ws, size_t ws_size,
                              hipStream_t stream) {
    const float* input = (const float*)d_in[0];
    const float* w1  = (const float*)d_in[1];
    const float* b1  = (const float*)d_in[2];
    const float* w2  = (const float*)d_in[3];
    const float* b2  = (const float*)d_in[4];
    const float* fw1 = (const float*)d_in[5];
    const float* fb1 = (const float*)d_in[6];
    const float* fw2 = (const float*)d_in[7];
    const float* fb2 = (const float*)d_in[8];
    const float* fw3 = (const float*)d_in[9];
    const float* fb3 = (const float*)d_in[10];
    float* ws  = (float*)d_ws;
    float* out = (float*)d_out;

    prep_kernel<<<6, 256, 0, stream>>>(w1, w2, fw1, fw2, fw3, ws);
    absmax_kernel<<<2048, 256, 0, stream>>>((const float4*)input,
                                            (int)((size_t)BATCH * 3072 / 4), ws + OFF_SCAL);
    conv1_kernel<<<(BATCH + 2) / 3, 256, 0, stream>>>(input, b1, ws);
    conv2_kernel<<<(BATCH + 2) / 3, 256, 0, stream>>>(b2, ws);
    fc1_kernel<<<BATCH / 8, 128, 0, stream>>>(fb1, ws);
    fc2_kernel<<<BATCH / 8, 128, 0, stream>>>(fb2, ws);
    fc3_kernel<<<BATCH / 256, 256, 0, stream>>>(fb3, out, ws);
}

// Round 6
// 977.514 us; speedup vs baseline: 1.4649x; 1.0225x over previous
//
#include <hip/hip_runtime.h>
#include <math.h>

#define BATCH 16384
#define EPSQ 1e-8f

// ---------------- ws layout (32-bit units) ----------------
// float scalars: [0] absmax_in, [1,2] conv1 max/negmax, [3,4] conv2, [5,6] fc1,
//                [7,8] fc2, [9] s_w1 [10] s_w2 [11] s_w3 [12] s_w4 [13] s_w5
#define OFF_SCAL 0
#define OFF_WPK1 16      // 180 u32  : conv1 sign-packs [6][3][5]{w0123,w4pack}
#define OFF_WPK2 196     // 960 u32  : conv2 sign-packs [16][6][5]{...}
#define OFF_FQ1  1156    // 12000 u32: fc1 signs [120][100]
#define OFF_FQ2  13156   // 2688 u32 : fc2 signs [84][32] (k>=30 zero)
#define OFF_FQ3  15844   // 240 u32  : fc3 signs [10][24] (k>=21 zero)
#define OFF_OUT1 16384   // B*1176 fp32 pooled conv1 preact
#define N_OUT1   (BATCH*1176)
#define OFF_OUT2 (OFF_OUT1+N_OUT1)   // B*400 fp32 pooled conv2 preact
#define N_OUT2   (BATCH*400)
#define OFF_P3   (OFF_OUT2+N_OUT2)   // B*120 fc1 preact
#define N_P3     (BATCH*120)
#define OFF_P4   (OFF_P3+N_P3)       // B*84 fc2 preact

__device__ inline int sdot4(unsigned int a, unsigned int b, int c) {
    return __builtin_amdgcn_sdot4((int)a, (int)b, c, false);
}

__device__ inline void atomicMaxF(float* addr, float val) {
    unsigned int* ua = (unsigned int*)addr;
    unsigned int old = *ua;
    while (__uint_as_float(old) < val) {
        unsigned int assumed = old;
        old = atomicCAS(ua, assumed, __float_as_uint(val));
        if (old == assumed) break;
    }
}

__device__ inline float waveMax(float v) {
    #pragma unroll
    for (int off = 32; off > 0; off >>= 1)
        v = fmaxf(v, __shfl_down(v, off, 64));
    return v;
}

__device__ inline void blockAtomicMax2(float vmax, float vnmax, float* gmax, float* gnmax) {
    __shared__ float sm[4], sn[4];
    float a = waveMax(vmax), b = waveMax(vnmax);
    int tid = threadIdx.x;
    if ((tid & 63) == 0) { sm[tid >> 6] = a; sn[tid >> 6] = b; }
    __syncthreads();
    if (tid == 0) {
        float m = fmaxf(fmaxf(sm[0], sm[1]), fmaxf(sm[2], sm[3]));
        float n = fmaxf(fmaxf(sn[0], sn[1]), fmaxf(sn[2], sn[3]));
        atomicMaxF(gmax, m);
        atomicMaxF(gnmax, n);
    }
}

__device__ inline void waveAtomicMax2(float vmax, float vnmax, float* gmax, float* gnmax) {
    float a = waveMax(vmax), b = waveMax(vnmax);
    if ((threadIdx.x & 63) == 0) { atomicMaxF(gmax, a); atomicMaxF(gnmax, b); }
}

// int8 fake-quant pieces (IEEE div matches jnp.round(x/s) bins)
__device__ inline float fq_elem(float x, float s) {
    float q = fminf(fmaxf(rintf(x / s), -128.0f), 127.0f);
    return q * s;
}

// qrelu returning INTEGER code r in [0,127] (value = r*s2)
__device__ inline int qrelu_code(float x, float s1, float s2) {
    float q = fq_elem(x, s1);
    q = fmaxf(q, 0.0f);
    return (int)fminf(fmaxf(rintf(q / s2), -128.0f), 127.0f);
}

__device__ inline void get_qrelu_scales(const float* scal, int slot, float& s1, float& s2) {
    float maxa = scal[slot], negm = scal[slot + 1];
    float absm = fmaxf(maxa, negm);
    s1 = fmaxf(absm / 127.0f, EPSQ);
    float qm = fminf(fmaxf(rintf(maxa / s1), -128.0f), 127.0f) * s1;
    s2 = fmaxf(fmaxf(qm, 0.0f) / 127.0f, EPSQ);
}

__device__ inline unsigned int sgn8(float w) { return (w >= 0.0f) ? 0x01u : 0xFFu; }

// bytes x..x+3 from a little-endian word array (static indices after unroll)
__device__ inline unsigned int u32at(const unsigned int* wv, int wi, int k) {
    return (k == 0) ? wv[wi]
        : __builtin_amdgcn_perm(wv[wi + 1], wv[wi], 0x03020100u + 0x01010101u * (unsigned)k);
}

// ---------------- prep: scalars + sign-pack all weights ----------------
__global__ __launch_bounds__(256) void prep_kernel(const float* __restrict__ w1,
        const float* __restrict__ w2, const float* __restrict__ fw1,
        const float* __restrict__ fw2, const float* __restrict__ fw3,
        float* __restrict__ wsf) {
    int blk = blockIdx.x, tid = threadIdx.x;
    unsigned int* wsu = (unsigned int*)wsf;
    if (blk == 0) {
        if (tid == 0) wsf[0] = 0.0f;
        else if (tid <= 8) wsf[tid] = -INFINITY;
        return;
    }
    const float* src = nullptr; int N = 0;
    if (blk == 1)      { src = w1;  N = 450; }
    else if (blk == 2) { src = w2;  N = 2400; }
    else if (blk == 3) { src = fw1; N = 48000; }
    else if (blk == 4) { src = fw2; N = 10080; }
    else               { src = fw3; N = 840; }
    __shared__ float red[256];
    float partial = 0.0f;
    for (int i = tid; i < N; i += 256) partial += fabsf(src[i]);
    red[tid] = partial;
    __syncthreads();
    for (int s = 128; s > 0; s >>= 1) {
        if (tid < s) red[tid] += red[tid + s];
        __syncthreads();
    }
    if (tid == 0) wsf[8 + blk] = red[0] / (float)N;   // ws[9..13]

    if (blk == 1) {
        for (int t = tid; t < 90; t += 256) {         // (c,ci,ky)
            const float* wp = w1 + t * 5;
            wsu[OFF_WPK1 + 2*t] = sgn8(wp[0]) | (sgn8(wp[1])<<8) | (sgn8(wp[2])<<16) | (sgn8(wp[3])<<24);
            wsu[OFF_WPK1 + 2*t + 1] = sgn8(wp[4]) << 24;
        }
    } else if (blk == 2) {
        for (int t = tid; t < 480; t += 256) {
            const float* wp = w2 + t * 5;
            wsu[OFF_WPK2 + 2*t] = sgn8(wp[0]) | (sgn8(wp[1])<<8) | (sgn8(wp[2])<<16) | (sgn8(wp[3])<<24);
            wsu[OFF_WPK2 + 2*t + 1] = sgn8(wp[4]) << 24;
        }
    } else if (blk == 3) {
        for (int i = tid; i < 12000; i += 256) {
            int j = i / 100, k = i % 100;
            const float* wp = fw1 + j * 400 + k * 4;
            wsu[OFF_FQ1 + i] = sgn8(wp[0]) | (sgn8(wp[1])<<8) | (sgn8(wp[2])<<16) | (sgn8(wp[3])<<24);
        }
    } else if (blk == 4) {
        for (int i = tid; i < 2688; i += 256) {
            int j = i >> 5, k = i & 31;
            unsigned int u = 0;
            if (k < 30) {
                const float* wp = fw2 + j * 120 + k * 4;
                u = sgn8(wp[0]) | (sgn8(wp[1])<<8) | (sgn8(wp[2])<<16) | (sgn8(wp[3])<<24);
            }
            wsu[OFF_FQ2 + i] = u;
        }
    } else {
        for (int i = tid; i < 240; i += 256) {
            int j = i / 24, k = i % 24;
            unsigned int u = 0;
            if (k < 21) {
                const float* wp = fw3 + j * 84 + k * 4;
                u = sgn8(wp[0]) | (sgn8(wp[1])<<8) | (sgn8(wp[2])<<16) | (sgn8(wp[3])<<24);
            }
            wsu[OFF_FQ3 + i] = u;
        }
    }
}

// ---------------- input abs-max ----------------
__global__ __launch_bounds__(256) void absmax_kernel(const float4* __restrict__ x, int n4,
                                                     float* __restrict__ gmax) {
    float m = 0.0f;
    int stride = gridDim.x * 256;
    for (int i = blockIdx.x * 256 + threadIdx.x; i < n4; i += stride) {
        float4 v = x[i];
        m = fmaxf(m, fmaxf(fmaxf(fabsf(v.x), fabsf(v.y)), fmaxf(fabsf(v.z), fabsf(v.w))));
    }
    m = waveMax(m);
    if ((threadIdx.x & 63) == 0) atomicMaxF(gmax, m);
}

// ---------------- conv1: 3 img/block, i8 codes in LDS, dot4 sliding conv ----------------
#define C1_ROWP 48
#define C1_CIS  (32*C1_ROWP)
#define C1_IMGS (3*C1_CIS)

template<int X0>
__device__ inline void c1_phase(const unsigned char* ib, const unsigned int* wpk, int c,
                                int* ip, int& gmax, int& gmin) {
    int a0[14], a1[14];
    #pragma unroll
    for (int i = 0; i < 14; i++) { a0[i] = 0; a1[i] = 0; }
    for (int ci = 0; ci < 3; ci++) {
        const unsigned int* wkp = &wpk[(c * 3 + ci) * 10];
        unsigned int wk0[5], wk4[5];
        #pragma unroll
        for (int ky = 0; ky < 5; ky++) { wk0[ky] = wkp[2*ky]; wk4[ky] = wkp[2*ky+1]; }
        #pragma unroll
        for (int r6 = 0; r6 < 6; r6++) {
            const unsigned char* rb = ib + ci * C1_CIS + r6 * C1_ROWP;
            unsigned int wv[5];
            if (X0 == 0) {
                uint4 q = *(const uint4*)rb;
                wv[0] = q.x; wv[1] = q.y; wv[2] = q.z; wv[3] = q.w;
                wv[4] = *(const unsigned int*)(rb + 16);
            } else {
                wv[0] = *(const unsigned int*)(rb + 12);
                uint4 q = *(const uint4*)(rb + 16);
                wv[1] = q.x; wv[2] = q.y; wv[3] = q.z; wv[4] = q.w;
            }
            unsigned int up[15];
            #pragma unroll
            for (int i = 0; i < 15; i++) {
                int xx = X0 + i;
                up[i] = u32at(wv, (xx >> 2) - (X0 >> 2), xx & 3);
            }
            if (r6 <= 4) {
                unsigned int w0 = wk0[r6], w4 = wk4[r6];
                #pragma unroll
                for (int i = 0; i < 14; i++) {
                    a0[i] = sdot4(up[i], w0, a0[i]);
                    a0[i] = sdot4(up[i+1], w4, a0[i]);
                }
            }
            if (r6 >= 1) {
                unsigned int w0 = wk0[r6-1], w4 = wk4[r6-1];
                #pragma unroll
                for (int i = 0; i < 14; i++) {
                    a1[i] = sdot4(up[i], w0, a1[i]);
                    a1[i] = sdot4(up[i+1], w4, a1[i]);
                }
            }
        }
    }
    #pragma unroll
    for (int i = 0; i < 14; i++) {
        gmax = max(gmax, max(a0[i], a1[i]));
        gmin = min(gmin, min(a0[i], a1[i]));
    }
    #pragma unroll
    for (int p = 0; p < 7; p++)
        ip[p] = max(max(a0[2*p], a0[2*p+1]), max(a1[2*p], a1[2*p+1]));
}

__global__ __launch_bounds__(256) void conv1_kernel(const float* __restrict__ x,
        const float* __restrict__ b1, float* __restrict__ wsf) {
    __shared__ unsigned char xq[3 * C1_IMGS];
    __shared__ unsigned int wpk[180];
    __shared__ float bsm[6];
    unsigned int* wsu = (unsigned int*)wsf;
    float* scal = wsf;
    float* out1 = wsf + OFF_OUT1;
    int tid = threadIdx.x;
    int b0 = blockIdx.x * 3;
    int nimg = min(3, BATCH - b0);
    float s0 = fmaxf(scal[0] / 127.0f, EPSQ);
    float seff = s0 * scal[9];

    const float4* xb = (const float4*)(x + (size_t)b0 * 3072);
    for (int i = tid; i < nimg * 768; i += 256) {
        float4 v = xb[i];
        int q0 = (int)fminf(fmaxf(rintf(v.x / s0), -128.f), 127.f);
        int q1 = (int)fminf(fmaxf(rintf(v.y / s0), -128.f), 127.f);
        int q2 = (int)fminf(fmaxf(rintf(v.z / s0), -128.f), 127.f);
        int q3 = (int)fminf(fmaxf(rintf(v.w / s0), -128.f), 127.f);
        unsigned int u = (q0 & 255) | ((q1 & 255) << 8) | ((q2 & 255) << 16)
                       | ((unsigned)(q3 & 255) << 24);
        int idx = i * 4;
        int img = idx / 3072, rem = idx % 3072;
        int ci = rem >> 10, r2 = rem & 1023;
        int row = r2 >> 5, col = r2 & 31;
        *(unsigned int*)&xq[img * C1_IMGS + ci * C1_CIS + row * C1_ROWP + col] = u;
    }
    for (int i = tid; i < 180; i += 256) wpk[i] = wsu[OFF_WPK1 + i];
    if (tid < 6) bsm[tid] = b1[tid];
    __syncthreads();

    float vmax = -INFINITY, vnmax = -INFINITY;
    if (tid < nimg * 84) {
        int img = tid / 84, r = tid % 84;
        int c = r / 14, py = r % 14;
        const unsigned char* ib = &xq[img * C1_IMGS + (2 * py) * C1_ROWP];
        int ip0[7], ip1[7];
        int gmax = -2000000000, gmin = 2000000000;
        c1_phase<0>(ib, wpk, c, ip0, gmax, gmin);
        c1_phase<14>(ib, wpk, c, ip1, gmax, gmin);
        float bias = bsm[c];
        float* dst = &out1[(size_t)(b0 + img) * 1176 + c * 196 + py * 14];
        #pragma unroll
        for (int p = 0; p < 7; p++) {
            dst[p]     = fmaf(seff, (float)ip0[p], bias);
            dst[7 + p] = fmaf(seff, (float)ip1[p], bias);
        }
        vmax  = fmaf(seff, (float)gmax, bias);
        vnmax = -fmaf(seff, (float)gmin, bias);
    }
    blockAtomicMax2(vmax, vnmax, scal + 1, scal + 2);
}

// ---------------- conv2: 3 img/block, i8 codes, dot4 ----------------
#define C2_ROWP 16
#define C2_CIS  (14*C2_ROWP)
#define C2_IMGS (6*C2_CIS)

__global__ __launch_bounds__(256) void conv2_kernel(const float* __restrict__ b2,
                                                    float* __restrict__ wsf) {
    __shared__ unsigned char act[3 * C2_IMGS];
    __shared__ unsigned int wpk[960];
    __shared__ float bsm[16];
    unsigned int* wsu = (unsigned int*)wsf;
    float* scal = wsf;
    const float* out1 = wsf + OFF_OUT1;
    float* out2 = wsf + OFF_OUT2;
    int tid = threadIdx.x;
    int b0 = blockIdx.x * 3;
    int nimg = min(3, BATCH - b0);
    float s1, s2;
    get_qrelu_scales(scal, 1, s1, s2);
    float seff = s2 * scal[10];

    for (int i = tid; i < nimg * 588; i += 256) {
        int img = i / 588, rem = i % 588;
        int e = rem * 2;
        int ci = e / 196, r2 = e % 196;
        int row = r2 / 14, col = r2 % 14;
        float2 v = *(const float2*)&out1[(size_t)(b0 + img) * 1176 + e];
        int r0 = qrelu_code(v.x, s1, s2);
        int r1 = qrelu_code(v.y, s1, s2);
        *(unsigned short*)&act[img * C2_IMGS + ci * C2_CIS + row * C2_ROWP + col] =
            (unsigned short)(r0 | (r1 << 8));
    }
    for (int i = tid; i < 960; i += 256) wpk[i] = wsu[OFF_WPK2 + i];
    if (tid < 16) bsm[tid] = b2[tid];
    __syncthreads();

    float vmax = -INFINITY, vnmax = -INFINITY;
    if (tid < nimg * 80) {
        int img = tid / 80, r = tid % 80;
        int c = r / 5, py = r % 5;
        const unsigned char* ib = &act[img * C2_IMGS + (2 * py) * C2_ROWP];
        int a0[10], a1[10];
        #pragma unroll
        for (int i = 0; i < 10; i++) { a0[i] = 0; a1[i] = 0; }
        for (int ci = 0; ci < 6; ci++) {
            const unsigned int* wkp = &wpk[(c * 6 + ci) * 10];
            unsigned int wk0[5], wk4[5];
            #pragma unroll
            for (int ky = 0; ky < 5; ky++) { wk0[ky] = wkp[2*ky]; wk4[ky] = wkp[2*ky+1]; }
            #pragma unroll
            for (int r6 = 0; r6 < 6; r6++) {
                const unsigned char* rb = ib + ci * C2_CIS + r6 * C2_ROWP;
                uint4 q = *(const uint4*)rb;
                unsigned int wv[4] = { q.x, q.y, q.z, q.w };
                unsigned int up[11];
                #pragma unroll
                for (int i = 0; i < 11; i++) up[i] = u32at(wv, i >> 2, i & 3);
                if (r6 <= 4) {
                    unsigned int w0 = wk0[r6], w4 = wk4[r6];
                    #pragma unroll
                    for (int i = 0; i < 10; i++) {
                        a0[i] = sdot4(up[i], w0, a0[i]);
                        a0[i] = sdot4(up[i+1], w4, a0[i]);
                    }
                }
                if (r6 >= 1) {
                    unsigned int w0 = wk0[r6-1], w4 = wk4[r6-1];
                    #pragma unroll
                    for (int i = 0; i < 10; i++) {
                        a1[i] = sdot4(up[i], w0, a1[i]);
                        a1[i] = sdot4(up[i+1], w4, a1[i]);
                    }
                }
            }
        }
        int gmax = -2000000000, gmin = 2000000000;
        #pragma unroll
        for (int i = 0; i < 10; i++) {
            gmax = max(gmax, max(a0[i], a1[i]));
            gmin = min(gmin, min(a0[i], a1[i]));
        }
        float bias = bsm[c];
        float* dst = &out2[(size_t)(b0 + img) * 400 + c * 25 + py * 5];
        #pragma unroll
        for (int p = 0; p < 5; p++) {
            int ip = max(max(a0[2*p], a0[2*p+1]), max(a1[2*p], a1[2*p+1]));
            dst[p] = fmaf(seff, (float)ip, bias);
        }
        vmax  = fmaf(seff, (float)gmax, bias);
        vnmax = -fmaf(seff, (float)gmin, bias);
    }
    blockAtomicMax2(vmax, vnmax, scal + 3, scal + 4);
}

// ---------------- fc1: [B,400]->[B,120], dot4, 8 rows/block ----------------
__global__ __launch_bounds__(128) void fc1_kernel(const float* __restrict__ fb1,
                                                  float* __restrict__ wsf) {
    __shared__ unsigned int xs[8][100];
    unsigned int* wsu = (unsigned int*)wsf;
    float* scal = wsf;
    const float* p2 = wsf + OFF_OUT2;
    float* p3 = wsf + OFF_P3;
    int tid = threadIdx.x;
    size_t row0 = (size_t)blockIdx.x * 8;
    float s1, s2;
    get_qrelu_scales(scal, 3, s1, s2);
    float seff = s2 * scal[11];
    const float4* src = (const float4*)(p2 + row0 * 400);
    for (int i = tid; i < 800; i += 128) {
        float4 v = src[i];
        int c0 = qrelu_code(v.x, s1, s2), c1 = qrelu_code(v.y, s1, s2);
        int c2 = qrelu_code(v.z, s1, s2), c3 = qrelu_code(v.w, s1, s2);
        xs[i / 100][i % 100] = c0 | (c1 << 8) | (c2 << 16) | ((unsigned)c3 << 24);
    }
    __syncthreads();
    float vmax = -INFINITY, vnmax = -INFINITY;
    if (tid < 120) {
        int j = tid;
        int acc[8];
        #pragma unroll
        for (int r = 0; r < 8; r++) acc[r] = 0;
        const uint4* wrow = (const uint4*)&wsu[OFF_FQ1 + j * 100];
        for (int kg = 0; kg < 25; kg++) {
            uint4 wv = wrow[kg];
            #pragma unroll
            for (int r = 0; r < 8; r++) {
                uint4 xv = *(const uint4*)&xs[r][kg * 4];
                acc[r] = sdot4(xv.x, wv.x, acc[r]);
                acc[r] = sdot4(xv.y, wv.y, acc[r]);
                acc[r] = sdot4(xv.z, wv.z, acc[r]);
                acc[r] = sdot4(xv.w, wv.w, acc[r]);
            }
        }
        float bias = fb1[j];
        #pragma unroll
        for (int r = 0; r < 8; r++) {
            float pv = fmaf(seff, (float)acc[r], bias);
            p3[(row0 + r) * 120 + j] = pv;
            vmax = fmaxf(vmax, pv); vnmax = fmaxf(vnmax, -pv);
        }
    }
    waveAtomicMax2(vmax, vnmax, scal + 5, scal + 6);
}

// ---------------- fc2: [B,120]->[B,84], dot4, 8 rows/block ----------------
__global__ __launch_bounds__(128) void fc2_kernel(const float* __restrict__ fb2,
                                                  float* __restrict__ wsf) {
    __shared__ unsigned int xs[8][32];
    unsigned int* wsu = (unsigned int*)wsf;
    float* scal = wsf;
    const float* p3 = wsf + OFF_P3;
    float* p4 = wsf + OFF_P4;
    int tid = threadIdx.x;
    size_t row0 = (size_t)blockIdx.x * 8;
    float s1, s2;
    get_qrelu_scales(scal, 5, s1, s2);
    float seff = s2 * scal[12];
    const float4* src = (const float4*)(p3 + row0 * 120);
    for (int i = tid; i < 240; i += 128) {
        float4 v = src[i];
        int c0 = qrelu_code(v.x, s1, s2), c1 = qrelu_code(v.y, s1, s2);
        int c2 = qrelu_code(v.z, s1, s2), c3 = qrelu_code(v.w, s1, s2);
        xs[i / 30][i % 30] = c0 | (c1 << 8) | (c2 << 16) | ((unsigned)c3 << 24);
    }
    if (tid < 16) xs[tid >> 1][30 + (tid & 1)] = 0;
    __syncthreads();
    float vmax = -INFINITY, vnmax = -INFINITY;
    if (tid < 84) {
        int j = tid;
        int acc[8];
        #pragma unroll
        for (int r = 0; r < 8; r++) acc[r] = 0;
        const uint4* wrow = (const uint4*)&wsu[OFF_FQ2 + j * 32];
        #pragma unroll
        for (int kg = 0; kg < 8; kg++) {
            uint4 wv = wrow[kg];
            #pragma unroll
            for (int r = 0; r < 8; r++) {
                uint4 xv = *(const uint4*)&xs[r][kg * 4];
                acc[r] = sdot4(xv.x, wv.x, acc[r]);
                acc[r] = sdot4(xv.y, wv.y, acc[r]);
                acc[r] = sdot4(xv.z, wv.z, acc[r]);
                acc[r] = sdot4(xv.w, wv.w, acc[r]);
            }
        }
        float bias = fb2[j];
        #pragma unroll
        for (int r = 0; r < 8; r++) {
            float pv = fmaf(seff, (float)acc[r], bias);
            p4[(row0 + r) * 84 + j] = pv;
            vmax = fmaxf(vmax, pv); vnmax = fmaxf(vnmax, -pv);
        }
    }
    waveAtomicMax2(vmax, vnmax, scal + 7, scal + 8);
}

// ---------------- fc3: [B,84]->[B,10], dot4, 1 row/thread ----------------
__global__ __launch_bounds__(256) void fc3_kernel(const float* __restrict__ fb3,
                                                  float* __restrict__ out,
                                                  float* __restrict__ wsf) {
    __shared__ unsigned int wsm[240];
    __shared__ float bs[10];
    unsigned int* wsu = (unsigned int*)wsf;
    float* scal = wsf;
    const float* p4 = wsf + OFF_P4;
    int tid = threadIdx.x;
    for (int i = tid; i < 240; i += 256) wsm[i] = wsu[OFF_FQ3 + i];
    if (tid < 10) bs[tid] = fb3[tid];
    __syncthreads();
    float s1, s2;
    get_qrelu_scales(scal, 7, s1, s2);
    float seff = s2 * scal[13];
    size_t row = (size_t)blockIdx.x * 256 + tid;
    unsigned int xr[24];
    const float4* src = (const float4*)(p4 + row * 84);
    #pragma unroll
    for (int k = 0; k < 21; k++) {
        float4 v = src[k];
        int c0 = qrelu_code(v.x, s1, s2), c1 = qrelu_code(v.y, s1, s2);
        int c2 = qrelu_code(v.z, s1, s2), c3 = qrelu_code(v.w, s1, s2);
        xr[k] = c0 | (c1 << 8) | (c2 << 16) | ((unsigned)c3 << 24);
    }
    xr[21] = 0; xr[22] = 0; xr[23] = 0;
    #pragma unroll
    for (int j = 0; j < 10; j++) {
        int acc = 0;
        #pragma unroll
        for (int k = 0; k < 24; k++) acc = sdot4(xr[k], wsm[j * 24 + k], acc);
        out[row * 10 + j] = fmaf(seff, (float)acc, bs[j]);
    }
}

extern "C" void kernel_launch(void* const* d_in, const int* in_sizes, int n_in,
                              void* d_out, int out_size, void* d_ws, size_t ws_size,
                              hipStream_t stream) {
    const float* input = (const float*)d_in[0];
    const float* w1  = (const float*)d_in[1];
    const float* b1  = (const float*)d_in[2];
    const float* w2  = (const float*)d_in[3];
    const float* b2  = (const float*)d_in[4];
    const float* fw1 = (const float*)d_in[5];
    const float* fb1 = (const float*)d_in[6];
    const float* fw2 = (const float*)d_in[7];
    const float* fb2 = (const float*)d_in[8];
    const float* fw3 = (const float*)d_in[9];
    const float* fb3 = (const float*)d_in[10];
    float* ws  = (float*)d_ws;
    float* out = (float*)d_out;

    prep_kernel<<<6, 256, 0, stream>>>(w1, w2, fw1, fw2, fw3, ws);
    absmax_kernel<<<2048, 256, 0, stream>>>((const float4*)input,
                                            (int)((size_t)BATCH * 3072 / 4), ws);
    conv1_kernel<<<(BATCH + 2) / 3, 256, 0, stream>>>(input, b1, ws);
    conv2_kernel<<<(BATCH + 2) / 3, 256, 0, stream>>>(b2, ws);
    fc1_kernel<<<BATCH / 8, 128, 0, stream>>>(fb1, ws);
    fc2_kernel<<<BATCH / 8, 128, 0, stream>>>(fb2, ws);
    fc3_kernel<<<BATCH / 256, 256, 0, stream>>>(fb3, out, ws);
}